// Round 1
// baseline (69.553 us; speedup 1.0000x reference)
//
#include <hip/hip_runtime.h>
#include <math.h>

// Problem constants (from setup_inputs): V=50000, D=100, B=16, S=128, U=100, L=2
#define NB 16
#define SS 128
#define DD 100
#define KK 100   // outputs per position per layer (= D = U)
#define NT 128   // threads per block

// ---------------------------------------------------------------------------
// Block-wide sum over NT threads via LDS tree. `red` must be float[NT].
// ---------------------------------------------------------------------------
__device__ __forceinline__ float block_reduce_sum(float v, float* red) {
  const int tid = threadIdx.x;
  red[tid] = v;
  __syncthreads();
  for (int off = NT / 2; off > 0; off >>= 1) {
    if (tid < off) red[tid] += red[tid + off];
    __syncthreads();
  }
  float r = red[0];
  __syncthreads();  // safe reuse of red afterwards
  return r;
}

// ---------------------------------------------------------------------------
// Stage 1: per (b,t) block — gather embedding row, L2-normalize amp, build
// phi0 = amp * e^{i*phase} in LDS, then m1[t,k] = |<v1_k, phi0_t>|^2 with
// v1 = row-normalized proj_kernel[0] (normalization folded in).
// Also writes wn[b,t] = ||amp|| and ew[b,t] = exp(wn).
// ---------------------------------------------------------------------------
__global__ __launch_bounds__(NT) void k_stage1(
    const int* __restrict__ seq,
    const float* __restrict__ ampT, const float* __restrict__ phT,
    const float* __restrict__ pkr, const float* __restrict__ pki,
    float* __restrict__ m1, float* __restrict__ ew, float* __restrict__ wn) {
  __shared__ float red[NT];
  __shared__ float xr[DD], xi[DD];
  const int bt  = blockIdx.x;  // b*SS + t
  const int tid = threadIdx.x;
  const int idx = seq[bt];

  float a = 0.f, p = 0.f;
  if (tid < DD) {
    a = ampT[(long)idx * DD + tid];
    p = phT[(long)idx * DD + tid];
  }
  const float nsq = block_reduce_sum(a * a, red);
  const float nrm = sqrtf(nsq);
  if (tid == 0) {
    wn[bt] = nrm;
    ew[bt] = expf(nrm);
  }
  if (tid < DD) {
    float sv, cv;
    sincosf(p, &sv, &cv);
    const float an = a / nrm;
    xr[tid] = an * cv;
    xi[tid] = an * sv;
  }
  __syncthreads();

  if (tid < KK) {
    const float* vr = pkr + tid * DD;  // proj layer 0, row tid
    const float* vi = pki + tid * DD;
    float cr = 0.f, ci = 0.f, vn = 0.f;
    for (int d = 0; d < DD; ++d) {
      const float r = vr[d], q = vi[d], br = xr[d], bi = xi[d];
      cr += r * br + q * bi;   // Re <v*, phi>
      ci += r * bi - q * br;   // Im <v*, phi>
      vn += r * r + q * q;     // row norm^2 (normalization folded in)
    }
    m1[bt * KK + tid] = (cr * cr + ci * ci) / vn;
  }
}

// ---------------------------------------------------------------------------
// Stage 2 (ngram n=2, proj layer 1): seq1[t,k] = sum_{j<2} gw[t,j]*m1pad[t+j,k]
// with gw[t,j] = exp(wn[t+j])/Z[j], Z[j] = E - prefix_j + j (pad exp(0)=1
// terms in denominator; numerator pad terms multiply zero states -> drop).
// Then m2[t,k] = |<v2_k, seq1_t>|^2 (seq1 real).
// ---------------------------------------------------------------------------
__global__ __launch_bounds__(NT) void k_stage2(
    const float* __restrict__ m1, const float* __restrict__ ew,
    const float* __restrict__ pkr, const float* __restrict__ pki,
    float* __restrict__ m2) {
  __shared__ float red[NT];
  __shared__ float es[SS];
  __shared__ float s1[DD];
  const int bt  = blockIdx.x;
  const int b   = bt / SS;
  const int t   = bt - b * SS;
  const int tid = threadIdx.x;

  const float e = ew[b * SS + tid];  // NT == SS
  es[tid] = e;
  const float E = block_reduce_sum(e, red);

  const float w0 = es[t] / E;
  const float w1 = ((t + 1 < SS) ? es[t + 1] : 1.0f) / (E - es[0] + 1.0f);

  if (tid < KK) {
    float v = w0 * m1[bt * KK + tid];
    if (t + 1 < SS) v += w1 * m1[(bt + 1) * KK + tid];
    s1[tid] = v;
  }
  __syncthreads();

  if (tid < KK) {
    const float* vr = pkr + DD * DD + tid * DD;  // proj layer 1, row tid
    const float* vi = pki + DD * DD + tid * DD;
    float cr = 0.f, ci = 0.f, vn = 0.f;
    for (int d = 0; d < DD; ++d) {
      const float r = vr[d], q = vi[d], x = s1[d];
      cr += r * x;
      ci -= q * x;
      vn += r * r + q * q;
    }
    m2[bt * KK + tid] = (cr * cr + ci * ci) / vn;
  }
}

// ---------------------------------------------------------------------------
// Stage 3 (ngram n=3 + measurement): seq2 from m2 with 3-tap window, then
// m3w[t,k] = wn[t] * |<u_k, seq2_t>|^2  (final mixture weight folded in).
// ---------------------------------------------------------------------------
__global__ __launch_bounds__(NT) void k_stage3(
    const float* __restrict__ m2, const float* __restrict__ ew,
    const float* __restrict__ wn,
    const float* __restrict__ ur, const float* __restrict__ ui,
    float* __restrict__ m3w) {
  __shared__ float red[NT];
  __shared__ float es[SS];
  __shared__ float s2[DD];
  const int bt  = blockIdx.x;
  const int b   = bt / SS;
  const int t   = bt - b * SS;
  const int tid = threadIdx.x;

  const float e = ew[b * SS + tid];
  es[tid] = e;
  const float E = block_reduce_sum(e, red);

  const float w0 = es[t] / E;
  const float w1 = ((t + 1 < SS) ? es[t + 1] : 1.0f) / (E - es[0] + 1.0f);
  const float w2 = ((t + 2 < SS) ? es[t + 2] : 1.0f) / (E - es[0] - es[1] + 2.0f);

  if (tid < KK) {
    float v = w0 * m2[bt * KK + tid];
    if (t + 1 < SS) v += w1 * m2[(bt + 1) * KK + tid];
    if (t + 2 < SS) v += w2 * m2[(bt + 2) * KK + tid];
    s2[tid] = v;
  }
  __syncthreads();

  if (tid < KK) {
    const float* vr = ur + tid * DD;  // meas kernel row tid
    const float* vi = ui + tid * DD;
    float cr = 0.f, ci = 0.f, vn = 0.f;
    for (int d = 0; d < DD; ++d) {
      const float r = vr[d], q = vi[d], x = s2[d];
      cr += r * x;
      ci -= q * x;
      vn += r * r + q * q;
    }
    m3w[bt * KK + tid] = wn[bt] * (cr * cr + ci * ci) / vn;
  }
}

// ---------------------------------------------------------------------------
// Stage 4: probs[b,k] = sum_t m3w[b,t,k]; out[b,:] = probs @ dense_w + dense_b
// ---------------------------------------------------------------------------
__global__ __launch_bounds__(NT) void k_out(
    const float* __restrict__ m3w, const float* __restrict__ dw,
    const float* __restrict__ db, float* __restrict__ out) {
  __shared__ float pr[KK];
  const int b   = blockIdx.x;
  const int tid = threadIdx.x;
  if (tid < KK) {
    float s = 0.f;
    for (int t = 0; t < SS; ++t) s += m3w[(b * SS + t) * KK + tid];
    pr[tid] = s;
  }
  __syncthreads();
  if (tid < 2) {
    float s = db[tid];
    for (int k = 0; k < KK; ++k) s += pr[k] * dw[k * 2 + tid];
    out[b * 2 + tid] = s;
  }
}

// ---------------------------------------------------------------------------
extern "C" void kernel_launch(void* const* d_in, const int* in_sizes, int n_in,
                              void* d_out, int out_size, void* d_ws, size_t ws_size,
                              hipStream_t stream) {
  const int*   seq  = (const int*)d_in[0];
  const float* ampT = (const float*)d_in[1];
  const float* phT  = (const float*)d_in[2];
  const float* pkr  = (const float*)d_in[3];
  const float* pki  = (const float*)d_in[4];
  const float* mkr  = (const float*)d_in[5];
  const float* mki  = (const float*)d_in[6];
  const float* dw   = (const float*)d_in[7];
  const float* db   = (const float*)d_in[8];
  float* out = (float*)d_out;

  float* ws = (float*)d_ws;
  const int M = NB * SS * KK;  // 204800 floats
  float* m1 = ws;              // stage-1 output; reused as m3w by stage 3
  float* m2 = ws + M;
  float* ew = ws + 2 * M;
  float* wn = ws + 2 * M + NB * SS;
  // total ws use: 2*M + 2*NB*SS floats = ~1.65 MB

  dim3 blk(NT);
  k_stage1<<<NB * SS, blk, 0, stream>>>(seq, ampT, phT, pkr, pki, m1, ew, wn);
  k_stage2<<<NB * SS, blk, 0, stream>>>(m1, ew, pkr, pki, m2);
  k_stage3<<<NB * SS, blk, 0, stream>>>(m2, ew, wn, mkr, mki, m1 /*m3w*/);
  k_out<<<NB, blk, 0, stream>>>(m1, dw, db, out);
}

// Round 2
// 48.071 us; speedup vs baseline: 1.4469x; 1.4469x over previous
//
#include <hip/hip_runtime.h>
#include <math.h>

// Problem constants: V=50000, D=100, B=16, S=128, U=100, L=2
#define NB 16
#define SS 128
#define DD 100
#define KK 100
#define NT 128

// ---------------------------------------------------------------------------
// 128-thread reduce: full-wave shfl_xor within each of the 2 waves, then
// combine the 2 partials through LDS (1 barrier). All 128 threads must call.
// ---------------------------------------------------------------------------
__device__ __forceinline__ float reduce128(float v, float* s2) {
  for (int m = 32; m; m >>= 1) v += __shfl_xor(v, m, 64);
  const int tid = threadIdx.x;
  if ((tid & 63) == 0) s2[tid >> 6] = v;
  __syncthreads();
  return s2[0] + s2[1];
}

// ---------------------------------------------------------------------------
// Prep: for mat in {proj0, proj1, meas}, row k: normalize row by its complex
// L2 norm and store TRANSPOSED: vT[d*KK + k] = v[k*DD + d] / ||v_k||.
// Grid: 3*KK blocks. Folds _normalize_complex into the tables once.
// ---------------------------------------------------------------------------
__global__ __launch_bounds__(NT) void k_prep(
    const float* __restrict__ pkr, const float* __restrict__ pki,
    const float* __restrict__ mkr, const float* __restrict__ mki,
    float* __restrict__ vT) {
  __shared__ float s2[2];
  const int mat = blockIdx.x / KK;
  const int k   = blockIdx.x % KK;
  const int tid = threadIdx.x;
  const float* sr = (mat == 0) ? pkr : (mat == 1) ? pkr + DD * DD : mkr;
  const float* si = (mat == 0) ? pki : (mat == 1) ? pki + DD * DD : mki;
  float r = 0.f, q = 0.f;
  if (tid < DD) { r = sr[k * DD + tid]; q = si[k * DD + tid]; }
  const float nsq = reduce128(r * r + q * q, s2);
  const float rn = 1.0f / sqrtf(nsq);
  if (tid < DD) {
    float* base = vT + mat * 2 * DD * KK;
    base[tid * KK + k]            = r * rn;  // real, transposed
    base[DD * KK + tid * KK + k]  = q * rn;  // imag, transposed
  }
}

// ---------------------------------------------------------------------------
// Stage 1: per (b,t): gather embedding row, L2-normalize amp, phi = amp*e^{ip}
// in LDS, then m1[bt,k] = |<v0_k, phi>|^2 with pre-normalized transposed v0.
// Also wn[bt] = ||amp||, ew[bt] = exp(||amp||).
// ---------------------------------------------------------------------------
__global__ __launch_bounds__(NT) void k_stage1(
    const int* __restrict__ seq,
    const float* __restrict__ ampT, const float* __restrict__ phT,
    const float* __restrict__ vTr, const float* __restrict__ vTi,
    float* __restrict__ m1, float* __restrict__ ew, float* __restrict__ wn) {
  __shared__ float s2[2];
  __shared__ float xr[DD], xi[DD];
  const int bt  = blockIdx.x;
  const int tid = threadIdx.x;
  const int idx = seq[bt];

  float a = 0.f, p = 0.f;
  if (tid < DD) {
    a = ampT[(long)idx * DD + tid];
    p = phT[(long)idx * DD + tid];
  }
  const float nrm = sqrtf(reduce128(a * a, s2));
  if (tid == 0) {
    wn[bt] = nrm;
    ew[bt] = expf(nrm);
  }
  if (tid < DD) {
    float sv, cv;
    sincosf(p, &sv, &cv);
    const float an = a / nrm;
    xr[tid] = an * cv;
    xi[tid] = an * sv;
  }
  __syncthreads();

  if (tid < KK) {
    float cr0 = 0.f, cr1 = 0.f, ci0 = 0.f, ci1 = 0.f;
#pragma unroll 5
    for (int d = 0; d < DD; d += 2) {
      const float vr0 = vTr[d * KK + tid],       vi0 = vTi[d * KK + tid];
      const float vr1 = vTr[(d + 1) * KK + tid], vi1 = vTi[(d + 1) * KK + tid];
      const float br0 = xr[d], bi0 = xi[d], br1 = xr[d + 1], bi1 = xi[d + 1];
      cr0 += vr0 * br0 + vi0 * bi0;
      ci0 += vr0 * bi0 - vi0 * br0;
      cr1 += vr1 * br1 + vi1 * bi1;
      ci1 += vr1 * bi1 - vi1 * br1;
    }
    const float cr = cr0 + cr1, ci = ci0 + ci1;
    m1[bt * KK + tid] = cr * cr + ci * ci;
  }
}

// ---------------------------------------------------------------------------
// Stage 2 (n=2 window + proj layer 1): s1[d] = sum_j w_j * m1[t+j, d];
// softmax-over-seq denominators in closed form (pad exp(0)=1 terms included,
// numerator pad terms multiply zero states -> dropped).
// m2[bt,k] = |<v1_k, s1>|^2  (s1 real).
// ---------------------------------------------------------------------------
__global__ __launch_bounds__(NT) void k_stage2(
    const float* __restrict__ m1, const float* __restrict__ ew,
    const float* __restrict__ vTr, const float* __restrict__ vTi,
    float* __restrict__ m2) {
  __shared__ float s2[2];
  __shared__ float es[SS];
  __shared__ float s1[DD];
  const int bt  = blockIdx.x;
  const int b   = bt >> 7;
  const int t   = bt & (SS - 1);
  const int tid = threadIdx.x;

  const float e = ew[b * SS + tid];
  es[tid] = e;
  const float E = reduce128(e, s2);

  const float w0 = es[t] / E;
  const float w1 = ((t + 1 < SS) ? es[t + 1] : 1.0f) / (E - es[0] + 1.0f);

  if (tid < KK) {
    float v = w0 * m1[bt * KK + tid];
    if (t + 1 < SS) v += w1 * m1[(bt + 1) * KK + tid];
    s1[tid] = v;
  }
  __syncthreads();

  if (tid < KK) {
    float cr0 = 0.f, cr1 = 0.f, ci0 = 0.f, ci1 = 0.f;
#pragma unroll 5
    for (int d = 0; d < DD; d += 2) {
      const float x0 = s1[d], x1 = s1[d + 1];
      cr0 += vTr[d * KK + tid] * x0;
      ci0 -= vTi[d * KK + tid] * x0;
      cr1 += vTr[(d + 1) * KK + tid] * x1;
      ci1 -= vTi[(d + 1) * KK + tid] * x1;
    }
    const float cr = cr0 + cr1, ci = ci0 + ci1;
    m2[bt * KK + tid] = cr * cr + ci * ci;
  }
}

// ---------------------------------------------------------------------------
// Stage 3 (n=3 window + measurement): m3w[bt,k] = wn[bt]*|<u_k, s2>|^2.
// ---------------------------------------------------------------------------
__global__ __launch_bounds__(NT) void k_stage3(
    const float* __restrict__ m2, const float* __restrict__ ew,
    const float* __restrict__ wn,
    const float* __restrict__ uTr, const float* __restrict__ uTi,
    float* __restrict__ m3w) {
  __shared__ float s2lds[2];
  __shared__ float es[SS];
  __shared__ float sx[DD];
  const int bt  = blockIdx.x;
  const int b   = bt >> 7;
  const int t   = bt & (SS - 1);
  const int tid = threadIdx.x;

  const float e = ew[b * SS + tid];
  es[tid] = e;
  const float E = reduce128(e, s2lds);

  const float w0 = es[t] / E;
  const float w1 = ((t + 1 < SS) ? es[t + 1] : 1.0f) / (E - es[0] + 1.0f);
  const float w2 = ((t + 2 < SS) ? es[t + 2] : 1.0f) / (E - es[0] - es[1] + 2.0f);

  if (tid < KK) {
    float v = w0 * m2[bt * KK + tid];
    if (t + 1 < SS) v += w1 * m2[(bt + 1) * KK + tid];
    if (t + 2 < SS) v += w2 * m2[(bt + 2) * KK + tid];
    sx[tid] = v;
  }
  __syncthreads();

  if (tid < KK) {
    float cr0 = 0.f, cr1 = 0.f, ci0 = 0.f, ci1 = 0.f;
#pragma unroll 5
    for (int d = 0; d < DD; d += 2) {
      const float x0 = sx[d], x1 = sx[d + 1];
      cr0 += uTr[d * KK + tid] * x0;
      ci0 -= uTi[d * KK + tid] * x0;
      cr1 += uTr[(d + 1) * KK + tid] * x1;
      ci1 -= uTi[(d + 1) * KK + tid] * x1;
    }
    const float cr = cr0 + cr1, ci = ci0 + ci1;
    m3w[bt * KK + tid] = wn[bt] * (cr * cr + ci * ci);
  }
}

// ---------------------------------------------------------------------------
// Stage 4: probs[b,k] = sum_t m3w[b,t,k]; out[b,:] = probs @ dense_w + dense_b
// ---------------------------------------------------------------------------
__global__ __launch_bounds__(NT) void k_out(
    const float* __restrict__ m3w, const float* __restrict__ dw,
    const float* __restrict__ db, float* __restrict__ out) {
  __shared__ float pr[KK];
  const int b   = blockIdx.x;
  const int tid = threadIdx.x;
  if (tid < KK) {
    float s = 0.f;
    for (int t = 0; t < SS; ++t) s += m3w[(b * SS + t) * KK + tid];
    pr[tid] = s;
  }
  __syncthreads();
  if (tid < 2) {
    float s = db[tid];
    for (int k = 0; k < KK; ++k) s += pr[k] * dw[k * 2 + tid];
    out[b * 2 + tid] = s;
  }
}

// ---------------------------------------------------------------------------
extern "C" void kernel_launch(void* const* d_in, const int* in_sizes, int n_in,
                              void* d_out, int out_size, void* d_ws, size_t ws_size,
                              hipStream_t stream) {
  const int*   seq  = (const int*)d_in[0];
  const float* ampT = (const float*)d_in[1];
  const float* phT  = (const float*)d_in[2];
  const float* pkr  = (const float*)d_in[3];
  const float* pki  = (const float*)d_in[4];
  const float* mkr  = (const float*)d_in[5];
  const float* mki  = (const float*)d_in[6];
  const float* dw   = (const float*)d_in[7];
  const float* db   = (const float*)d_in[8];
  float* out = (float*)d_out;

  float* ws = (float*)d_ws;
  // Transposed, pre-normalized kernels: 3 mats x (r,i) x 10000 floats
  float* vT   = ws;                  // 60000 floats
  float* vT0r = vT;
  float* vT0i = vT + DD * KK;
  float* vT1r = vT + 2 * DD * KK;
  float* vT1i = vT + 3 * DD * KK;
  float* uTr  = vT + 4 * DD * KK;
  float* uTi  = vT + 5 * DD * KK;
  const int M = NB * SS * KK;        // 204800
  float* m1 = ws + 6 * DD * KK;      // reused as m3w in stage 3
  float* m2 = m1 + M;
  float* ew = m2 + M;
  float* wn = ew + NB * SS;
  // total ws: ~1.9 MB

  dim3 blk(NT);
  k_prep  <<<3 * KK,  blk, 0, stream>>>(pkr, pki, mkr, mki, vT);
  k_stage1<<<NB * SS, blk, 0, stream>>>(seq, ampT, phT, vT0r, vT0i, m1, ew, wn);
  k_stage2<<<NB * SS, blk, 0, stream>>>(m1, ew, vT1r, vT1i, m2);
  k_stage3<<<NB * SS, blk, 0, stream>>>(m2, ew, wn, uTr, uTi, m1 /*m3w*/);
  k_out   <<<NB,      blk, 0, stream>>>(m1, dw, db, out);
}

// Round 3
// 35.459 us; speedup vs baseline: 1.9615x; 1.3557x over previous
//
#include <hip/hip_runtime.h>
#include <math.h>

// Problem constants: V=50000, D=100, B=16, S=128, U=100, L=2
#define NB 16
#define SS 128
#define DD 100
#define KK 100
#define T_TILE 8            // output positions per block
#define P_HALO 11           // T_TILE + 3 (dependency cone)
#define NTILES 16           // SS / T_TILE
#define NT 768              // threads per block (12 waves, 3/SIMD)
#define NWAVES 12
#define CH_D4 5             // d4-rows per chunk
#define NCHUNK 5            // 25 d4-rows total (D=100)

// ---------------------------------------------------------------------------
// Per-chunk accumulate: slot = (p, k). V chunk in LDS as float4 (4 consecutive
// d's of one part), x broadcast from LDS float4 rows.
// MODE 0: complex x (stage 1).  MODE 1: real x (stages 2, 3).
// ---------------------------------------------------------------------------
template<int MODE>
__device__ __forceinline__ void accum_slot(
    const float4* __restrict__ vtb,
    const float4 (*__restrict__ bxr)[25], const float4 (*__restrict__ bxi)[25],
    int p, int k, int c, float& ar, float& ai)
{
#pragma unroll
  for (int r = 0; r < CH_D4; ++r) {
    const int d4 = c * CH_D4 + r;
    const float4 vr4 = vtb[r * KK + k];
    const float4 vi4 = vtb[500 + r * KK + k];
    const float4 x4  = bxr[p][d4];
    if (MODE == 0) {
      const float4 z4 = bxi[p][d4];
      ar += vr4.x * x4.x + vr4.y * x4.y + vr4.z * x4.z + vr4.w * x4.w
          + vi4.x * z4.x + vi4.y * z4.y + vi4.z * z4.z + vi4.w * z4.w;
      ai += vr4.x * z4.x + vr4.y * z4.y + vr4.z * z4.z + vr4.w * z4.w
          - vi4.x * x4.x - vi4.y * x4.y - vi4.z * x4.z - vi4.w * x4.w;
    } else {
      ar += vr4.x * x4.x + vr4.y * x4.y + vr4.z * x4.z + vr4.w * x4.w;
      ai += vi4.x * x4.x + vi4.y * x4.y + vi4.z * x4.z + vi4.w * x4.w;
    }
  }
}

// ---------------------------------------------------------------------------
// One projection stage: row-norm pass, chunked double-buffered transpose of
// the 100x100 complex matrix into LDS, dot products for all slots.
// MODE 0: writes m[p][k] = (ar^2+ai^2)*invvn[k].  MODE 1: writes y2 = (ar,ai).
// Caller must __syncthreads() after return before consuming outputs.
// ---------------------------------------------------------------------------
template<int MODE>
__device__ __forceinline__ void run_stage(
    const float* __restrict__ gvr, const float* __restrict__ gvi,
    float4 (*__restrict__ vt)[1000],
    const float4 (*__restrict__ bxr)[25], const float4 (*__restrict__ bxi)[25],
    float* __restrict__ mflat, float2* __restrict__ y2flat,
    float* __restrict__ invvn, const int nslots,
    const int tid, const int lane, const int wid)
{
  // --- row norms of this stage's matrix (4 lanes per row) ---
  if (tid < 4 * KK) {
    const int k = tid >> 2, q = tid & 3;
    const float* r0 = gvr + k * DD + q;
    const float* i0 = gvi + k * DD + q;
    float s = 0.f;
#pragma unroll
    for (int i = 0; i < 25; ++i) { const float a = r0[4*i], c2 = i0[4*i]; s += a*a + c2*c2; }
    s += __shfl_xor(s, 1, 64);
    s += __shfl_xor(s, 2, 64);
    if (q == 0) invvn[k] = 1.0f / s;
  }

  // element e of a chunk: part=e/500, r=(e%500)/100, k=e%100
  // global source: gv_part + k*DD + 4*(c*CH_D4 + r)   (16B aligned)
  const int e0 = tid;                 // always < 1000
  const int e1 = tid + NT;            // valid for tid < 232
  const int p0 = e0 / 500, rm0 = e0 % 500, r0_ = rm0 / 100, k0_ = rm0 % 100;
  const int p1 = e1 / 500, rm1 = e1 % 500, r1_ = rm1 / 100, k1_ = rm1 % 100;
  const float* g0 = (p0 ? gvi : gvr) + k0_ * DD + 4 * r0_;
  const float* g1 = (p1 ? gvi : gvr) + k1_ * DD + 4 * r1_;

  float4 pv0, pv1;
  pv0 = *(const float4*)(g0);                      // chunk 0
  if (e1 < 1000) pv1 = *(const float4*)(g1);
  vt[0][e0] = pv0;
  if (e1 < 1000) vt[0][e1] = pv1;
  __syncthreads();

  const int s0 = wid, s1 = wid + NWAVES;
  float a0r = 0.f, a0i = 0.f, a1r = 0.f, a1i = 0.f;
  const int kk0 = (s0 & 1) * 50 + lane;
  const int kk1 = (s1 & 1) * 50 + lane;
  const int pp0 = s0 >> 1, pp1 = s1 >> 1;

  for (int c = 0; c < NCHUNK; ++c) {
    const int buf = c & 1;
    if (c + 1 < NCHUNK) {                           // issue next-chunk loads early
      pv0 = *(const float4*)(g0 + 4 * CH_D4 * (c + 1));
      if (e1 < 1000) pv1 = *(const float4*)(g1 + 4 * CH_D4 * (c + 1));
    }
    if (lane < 50) {
      if (s0 < nslots) accum_slot<MODE>(vt[buf], bxr, bxi, pp0, kk0, c, a0r, a0i);
      if (s1 < nslots) accum_slot<MODE>(vt[buf], bxr, bxi, pp1, kk1, c, a1r, a1i);
    }
    if (c + 1 < NCHUNK) {                           // write-late into other buffer
      const int nb = buf ^ 1;
      vt[nb][e0] = pv0;
      if (e1 < 1000) vt[nb][e1] = pv1;
    }
    __syncthreads();
  }

  if (lane < 50) {
    if (s0 < nslots) {
      if (MODE == 0) mflat[pp0 * KK + kk0] = (a0r * a0r + a0i * a0i) * invvn[kk0];
      else           y2flat[pp0 * KK + kk0] = make_float2(a0r, a0i);
    }
    if (s1 < nslots) {
      if (MODE == 0) mflat[pp1 * KK + kk1] = (a1r * a1r + a1i * a1i) * invvn[kk1];
      else           y2flat[pp1 * KK + kk1] = make_float2(a1r, a1i);
    }
  }
}

// ---------------------------------------------------------------------------
// Fused kernel: block = (batch, tile of 8 positions). Computes the full
// 3-stage pipeline for its halo cone (11 positions) and writes partial probs.
// ---------------------------------------------------------------------------
__global__ __launch_bounds__(NT) void k_fused(
    const int* __restrict__ seq,
    const float* __restrict__ ampT, const float* __restrict__ phT,
    const float* __restrict__ pkr, const float* __restrict__ pki,
    const float* __restrict__ mkr, const float* __restrict__ mki,
    float* __restrict__ part)
{
  __shared__ float4 vt[2][1000];        // 32000 B: V chunk double-buffer
  __shared__ float4 xr4[P_HALO][25];    // stage-1 phi real
  __shared__ float4 xi4[P_HALO][25];    // stage-1 phi imag
  __shared__ float4 m4[P_HALO][25];     // m vector (m1, then m2, then scratch)
  __shared__ float2 y2[P_HALO][KK];     // projection pair outputs
  __shared__ float es[SS];
  __shared__ float wnl[SS];
  __shared__ float invvn[KK];
  __shared__ float redw[NWAVES];
  __shared__ float sc[3];               // E, Z1, Z2

  const int tid  = threadIdx.x;
  const int lane = tid & 63;
  const int wid  = tid >> 6;
  const int bt   = blockIdx.x;
  const int b    = bt >> 4;
  const int tile = bt & 15;
  const int t0   = tile * T_TILE;
  const int sb   = b * SS;

  // --- prologue A: norms + exp for ALL 128 positions of this batch ---
  if (tid < 4 * SS) {                   // waves 0..7 exactly
    const int t = tid >> 2, q = tid & 3;
    const int row = seq[sb + t];
    const float* ap = ampT + (long)row * DD + q;
    float s = 0.f;
#pragma unroll
    for (int i = 0; i < 25; ++i) { const float a = ap[4*i]; s += a * a; }
    s += __shfl_xor(s, 1, 64);
    s += __shfl_xor(s, 2, 64);
    if (q == 0) { const float nrm = sqrtf(s); wnl[t] = nrm; es[t] = expf(nrm); }
  }
  __syncthreads();

  // --- E and closed-form softmax denominators ---
  {
    float v = (tid < SS) ? es[tid] : 0.f;
    for (int m = 32; m; m >>= 1) v += __shfl_xor(v, m, 64);
    if (lane == 0) redw[wid] = v;
  }
  // --- prologue B: phi = (amp/||amp||) * e^{i phase} for halo positions ---
  for (int idx = tid; idx < P_HALO * 25; idx += NT) {
    const int p = idx / 25, d4 = idx % 25;
    const int tp = t0 + p;
    float4 o_r = {0.f, 0.f, 0.f, 0.f}, o_i = {0.f, 0.f, 0.f, 0.f};
    if (tp < SS) {
      const int row = seq[sb + tp];
      const float4 a4 = *(const float4*)(ampT + (long)row * DD + 4 * d4);
      const float4 p4 = *(const float4*)(phT  + (long)row * DD + 4 * d4);
      const float inv = 1.0f / wnl[tp];
      float sv, cv;
      sincosf(p4.x, &sv, &cv); o_r.x = a4.x * inv * cv; o_i.x = a4.x * inv * sv;
      sincosf(p4.y, &sv, &cv); o_r.y = a4.y * inv * cv; o_i.y = a4.y * inv * sv;
      sincosf(p4.z, &sv, &cv); o_r.z = a4.z * inv * cv; o_i.z = a4.z * inv * sv;
      sincosf(p4.w, &sv, &cv); o_r.w = a4.w * inv * cv; o_i.w = a4.w * inv * sv;
    }
    xr4[p][d4] = o_r;
    xi4[p][d4] = o_i;
  }
  __syncthreads();
  if (tid == 0) {
    float E = 0.f;
    for (int w = 0; w < NWAVES; ++w) E += redw[w];
    sc[0] = E;
    sc[1] = E - es[0] + 1.0f;
    sc[2] = E - es[0] - es[1] + 2.0f;
  }
  __syncthreads();

  // --- stage 1: m1[p][k] = |<v0_k, phi_p>|^2 / ||v0_k||^2 ---
  run_stage<0>(pkr, pki, vt, xr4, xi4, (float*)m4, nullptr, invvn,
               2 * P_HALO, tid, lane, wid);
  __syncthreads();

  // --- stage 2: y2[p][k] = (sum vr*m1, sum vi*m1) for proj layer 1 ---
  run_stage<1>(pkr + DD * DD, pki + DD * DD, vt, m4, m4, nullptr,
               (float2*)y2, invvn, 2 * P_HALO, tid, lane, wid);
  __syncthreads();

  // --- m2 = 2-tap window of y2, squared, scaled by invvn (layer-1 norms) ---
  {
    const float E = sc[0], Z1 = sc[1];
    for (int idx = tid; idx < 10 * KK; idx += NT) {
      const int p = idx / KK, k = idx - p * KK;
      const int t = t0 + p;
      const float w0 = ((t     < SS) ? es[t]     : 1.f) / E;
      const float w1 = ((t + 1 < SS) ? es[t + 1] : 1.f) / Z1;
      const float2 ya = y2[p][k], yb = y2[p + 1][k];
      const float ar = w0 * ya.x + w1 * yb.x;
      const float ai = w0 * ya.y + w1 * yb.y;
      ((float*)m4)[p * KK + k] = (ar * ar + ai * ai) * invvn[k];
    }
  }
  __syncthreads();

  // --- stage 3: y2[p][k] = (sum ur*m2, sum ui*m2), p < 10 ---
  run_stage<1>(mkr, mki, vt, m4, m4, nullptr,
               (float2*)y2, invvn, 20, tid, lane, wid);
  __syncthreads();

  // --- final: 3-tap window, square, * wn[t] * invvn_U[k]; sum over own p ---
  {
    const float E = sc[0], Z1 = sc[1], Z2 = sc[2];
    for (int idx = tid; idx < T_TILE * KK; idx += NT) {
      const int p = idx / KK, k = idx - p * KK;
      const int t = t0 + p;                         // < 128 always
      const float w0 = es[t] / E;
      const float w1 = ((t + 1 < SS) ? es[t + 1] : 1.f) / Z1;
      const float w2 = ((t + 2 < SS) ? es[t + 2] : 1.f) / Z2;
      const float2 ya = y2[p][k], yb = y2[p + 1][k], yc = y2[p + 2][k];
      const float qr = w0 * ya.x + w1 * yb.x + w2 * yc.x;
      const float qi = w0 * ya.y + w1 * yb.y + w2 * yc.y;
      ((float*)m4)[p * KK + k] = wnl[t] * (qr * qr + qi * qi) * invvn[k];
    }
  }
  __syncthreads();
  if (tid < KK) {
    float s = 0.f;
#pragma unroll
    for (int p = 0; p < T_TILE; ++p) s += ((float*)m4)[p * KK + tid];
    part[bt * KK + tid] = s;
  }
}

// ---------------------------------------------------------------------------
// Output: probs[b,k] = sum_tiles part; out = probs @ dense_w + dense_b
// ---------------------------------------------------------------------------
__global__ __launch_bounds__(128) void k_out(
    const float* __restrict__ part, const float* __restrict__ dw,
    const float* __restrict__ db, float* __restrict__ out)
{
  __shared__ float pr[KK];
  const int b = blockIdx.x, tid = threadIdx.x;
  if (tid < KK) {
    float s = 0.f;
#pragma unroll
    for (int q = 0; q < NTILES; ++q) s += part[(b * NTILES + q) * KK + tid];
    pr[tid] = s;
  }
  __syncthreads();
  if (tid < 2) {
    float s = db[tid];
    for (int k = 0; k < KK; ++k) s += pr[k] * dw[k * 2 + tid];
    out[b * 2 + tid] = s;
  }
}

// ---------------------------------------------------------------------------
extern "C" void kernel_launch(void* const* d_in, const int* in_sizes, int n_in,
                              void* d_out, int out_size, void* d_ws, size_t ws_size,
                              hipStream_t stream) {
  const int*   seq  = (const int*)d_in[0];
  const float* ampT = (const float*)d_in[1];
  const float* phT  = (const float*)d_in[2];
  const float* pkr  = (const float*)d_in[3];
  const float* pki  = (const float*)d_in[4];
  const float* mkr  = (const float*)d_in[5];
  const float* mki  = (const float*)d_in[6];
  const float* dw   = (const float*)d_in[7];
  const float* db   = (const float*)d_in[8];
  float* out  = (float*)d_out;
  float* part = (float*)d_ws;                 // 256*100 floats = 102.4 KB

  k_fused<<<NB * NTILES, NT, 0, stream>>>(seq, ampT, phT, pkr, pki, mkr, mki, part);
  k_out  <<<NB,          128, 0, stream>>>(part, dw, db, out);
}